// Round 3
// baseline (340.712 us; speedup 1.0000x reference)
//
#include <hip/hip_runtime.h>
#include <hip/hip_bf16.h>

#define B_SEG 16384
#define R_EDGE 262144
#define DKDIM 512
#define DOUT 512

typedef __attribute__((ext_vector_type(4))) float f32x4;
typedef __attribute__((ext_vector_type(8))) short bf16x8;

static __device__ __forceinline__ unsigned short f2bf(float f) {
    union { float f; unsigned int u; } v; v.f = f;
    unsigned int r = (v.u + 0x7FFFu + ((v.u >> 16) & 1u)) >> 16;
    return (unsigned short)r;
}

static __device__ __forceinline__ float dot8(const float4 qa, const float4 qb,
                                             const float4 ka, const float4 kb) {
    return qa.x * ka.x + qa.y * ka.y + qa.z * ka.z + qa.w * ka.w
         + qb.x * kb.x + qb.y * kb.y + qb.z * kb.z + qb.w * kb.w;
}

// ---------------- Stage 1: fused segment attention (one wave per segment) ----
// Online softmax over the segment's K rows; K read exactly once from HBM.
// 4-edge unroll + 1-deep software pipeline: next 4 rows load while the
// current 4 rows' shfl/exp/rescale chain runs.
__global__ __launch_bounds__(256) void attn_kernel(
    const float* __restrict__ Q, const float* __restrict__ K,
    const int* __restrict__ td, unsigned short* __restrict__ ctxb)
{
    const int w = threadIdx.x >> 6;
    const int lane = threadIdx.x & 63;
    const int b = blockIdx.x * 4 + w;

    // lower_bound(td, b) and lower_bound(td, b+1) — td is sorted.
    int lo = 0, hi = R_EDGE;
    while (lo < hi) { int mid = (lo + hi) >> 1; if (td[mid] < b) lo = mid + 1; else hi = mid; }
    const int s0 = lo;
    hi = R_EDGE;
    while (lo < hi) { int mid = (lo + hi) >> 1; if (td[mid] < b + 1) lo = mid + 1; else hi = mid; }
    const int s1 = lo;

    // Q row: lane holds elems [4*lane .. 4*lane+3] and [256+4*lane .. +3]
    const float4* Q4 = (const float4*)(Q + (size_t)b * DKDIM);
    const float4 qa = Q4[lane];
    const float4 qb = Q4[64 + lane];

    float m = -INFINITY, l = 0.0f;
    float c0 = 0.f, c1 = 0.f, c2 = 0.f, c3 = 0.f;
    float c4 = 0.f, c5 = 0.f, c6 = 0.f, c7 = 0.f;

    float4 ka0, kb0, ka1, kb1, ka2, kb2, ka3, kb3;

#define LOAD4(dst_a0, dst_b0, dst_a1, dst_b1, dst_a2, dst_b2, dst_a3, dst_b3, ee)            \
    {                                                                                        \
        const float4* K0_ = (const float4*)(K + (size_t)((ee) + 0) * DKDIM);                 \
        const float4* K1_ = (const float4*)(K + (size_t)((ee) + 1) * DKDIM);                 \
        const float4* K2_ = (const float4*)(K + (size_t)((ee) + 2) * DKDIM);                 \
        const float4* K3_ = (const float4*)(K + (size_t)((ee) + 3) * DKDIM);                 \
        dst_a0 = K0_[lane]; dst_b0 = K0_[64 + lane];                                         \
        dst_a1 = K1_[lane]; dst_b1 = K1_[64 + lane];                                         \
        dst_a2 = K2_[lane]; dst_b2 = K2_[64 + lane];                                         \
        dst_a3 = K3_[lane]; dst_b3 = K3_[64 + lane];                                         \
    }

#define PROC4()                                                                              \
    {                                                                                        \
        float p0 = dot8(qa, qb, ka0, kb0);                                                   \
        float p1 = dot8(qa, qb, ka1, kb1);                                                   \
        float p2 = dot8(qa, qb, ka2, kb2);                                                   \
        float p3 = dot8(qa, qb, ka3, kb3);                                                   \
        _Pragma("unroll")                                                                    \
        for (int off = 32; off >= 1; off >>= 1) {                                            \
            p0 += __shfl_xor(p0, off, 64);                                                   \
            p1 += __shfl_xor(p1, off, 64);                                                   \
            p2 += __shfl_xor(p2, off, 64);                                                   \
            p3 += __shfl_xor(p3, off, 64);                                                   \
        }                                                                                    \
        const float nm = fmaxf(fmaxf(fmaxf(p0, p1), fmaxf(p2, p3)), m);                      \
        const float sc = __expf(m - nm);                                                     \
        const float w0 = __expf(p0 - nm), w1 = __expf(p1 - nm);                              \
        const float w2 = __expf(p2 - nm), w3 = __expf(p3 - nm);                              \
        l = l * sc + ((w0 + w1) + (w2 + w3));                                                \
        c0 = c0 * sc + (w0 * ka0.x + w1 * ka1.x) + (w2 * ka2.x + w3 * ka3.x);                \
        c1 = c1 * sc + (w0 * ka0.y + w1 * ka1.y) + (w2 * ka2.y + w3 * ka3.y);                \
        c2 = c2 * sc + (w0 * ka0.z + w1 * ka1.z) + (w2 * ka2.z + w3 * ka3.z);                \
        c3 = c3 * sc + (w0 * ka0.w + w1 * ka1.w) + (w2 * ka2.w + w3 * ka3.w);                \
        c4 = c4 * sc + (w0 * kb0.x + w1 * kb1.x) + (w2 * kb2.x + w3 * kb3.x);                \
        c5 = c5 * sc + (w0 * kb0.y + w1 * kb1.y) + (w2 * kb2.y + w3 * kb3.y);                \
        c6 = c6 * sc + (w0 * kb0.z + w1 * kb1.z) + (w2 * kb2.z + w3 * kb3.z);                \
        c7 = c7 * sc + (w0 * kb0.w + w1 * kb1.w) + (w2 * kb2.w + w3 * kb3.w);                \
        m = nm;                                                                              \
    }

    int e = s0;
    if (s1 - s0 >= 4) {
        LOAD4(ka0, kb0, ka1, kb1, ka2, kb2, ka3, kb3, e);
        for (; e + 7 < s1; e += 4) {
            float4 na0, nb0, na1, nb1, na2, nb2, na3, nb3;
            LOAD4(na0, nb0, na1, nb1, na2, nb2, na3, nb3, e + 4);   // prefetch next
            PROC4();                                                 // compute current
            ka0 = na0; kb0 = nb0; ka1 = na1; kb1 = nb1;
            ka2 = na2; kb2 = nb2; ka3 = na3; kb3 = nb3;
        }
        PROC4();
        e += 4;
    }
    for (; e < s1; ++e) {
        const float4* K4 = (const float4*)(K + (size_t)e * DKDIM);
        const float4 ka = K4[lane];
        const float4 kb = K4[64 + lane];
        float p = dot8(qa, qb, ka, kb);
        #pragma unroll
        for (int off = 32; off >= 1; off >>= 1) p += __shfl_xor(p, off, 64);
        const float nm  = fmaxf(m, p);
        const float sc  = __expf(m - nm);
        const float wgt = __expf(p - nm);
        l = l * sc + wgt;
        c0 = c0 * sc + wgt * ka.x;  c1 = c1 * sc + wgt * ka.y;
        c2 = c2 * sc + wgt * ka.z;  c3 = c3 * sc + wgt * ka.w;
        c4 = c4 * sc + wgt * kb.x;  c5 = c5 * sc + wgt * kb.y;
        c6 = c6 * sc + wgt * kb.z;  c7 = c7 * sc + wgt * kb.w;
        m = nm;
    }

    const float rin = (s1 > s0) ? (1.0f / l) : 0.0f;  // empty segment -> ctx = 0
    ushort4 oa, ob;
    oa.x = f2bf(c0 * rin); oa.y = f2bf(c1 * rin); oa.z = f2bf(c2 * rin); oa.w = f2bf(c3 * rin);
    ob.x = f2bf(c4 * rin); ob.y = f2bf(c5 * rin); ob.z = f2bf(c6 * rin); ob.w = f2bf(c7 * rin);
    ushort4* O4 = (ushort4*)(ctxb + (size_t)b * DKDIM);
    O4[lane]      = oa;
    O4[64 + lane] = ob;
}

// ---------------- Stage 2a: W_o -> bf16, transposed (n-major) ----------------
__global__ __launch_bounds__(256) void wt_kernel(const float* __restrict__ W,
                                                 unsigned short* __restrict__ Wt)
{
    const int n = blockIdx.x;       // 512 blocks: one output column each
    for (int k = threadIdx.x; k < DKDIM; k += 256)
        Wt[(size_t)n * DKDIM + k] = f2bf(W[(size_t)k * DOUT + n]);
}

// ---------------- Stage 2b: out = ctx @ W_o + b_o via bf16 MFMA --------------
// No LDS: fragments read directly from L2-resident ctx-bf16 and Wt.
// Each wave computes a 64x32 output tile (4 m-frags x 2 n-frags).
// XCD-aware block swizzle: 128 consecutive block-ids per XCD -> each XCD's
// working set is 32 m-tiles of A (2 MB) + all of B (0.5 MB), L2-resident.
__global__ __launch_bounds__(256) void proj_kernel(
    const unsigned short* __restrict__ A,   // ctx bf16, [16384][512] row-major
    const unsigned short* __restrict__ Bt,  // W_o^T bf16, [512 n][512 k]
    const float* __restrict__ bias, float* __restrict__ out)
{
    const int w = threadIdx.x >> 6, lane = threadIdx.x & 63;
    // bijective XCD swizzle: gridDim.x = 1024, 1024 % 8 == 0
    const int cpx = (int)gridDim.x >> 3;    // 128 blocks per XCD chunk
    const int bid = (blockIdx.x & 7) * cpx + (blockIdx.x >> 3);
    const int gw   = bid * 4 + w;           // 0..4095
    const int mrow = (gw >> 4) << 6;        // 256 row-tiles of 64
    const int ncol = (gw & 15) << 5;        // 16 col-tiles of 32
    const int lr = lane & 15, lg = lane >> 4;

    f32x4 acc[4][2];
    #pragma unroll
    for (int i = 0; i < 4; ++i)
        #pragma unroll
        for (int j = 0; j < 2; ++j)
            acc[i][j] = (f32x4){0.f, 0.f, 0.f, 0.f};

    for (int k0 = 0; k0 < DKDIM; k0 += 32) {
        const int koff = k0 + lg * 8;
        bf16x8 af[4], bfr[2];
        #pragma unroll
        for (int i = 0; i < 4; ++i)
            af[i] = *(const bf16x8*)(A + (size_t)(mrow + i * 16 + lr) * DKDIM + koff);
        #pragma unroll
        for (int j = 0; j < 2; ++j)
            bfr[j] = *(const bf16x8*)(Bt + (size_t)(ncol + j * 16 + lr) * DKDIM + koff);
        #pragma unroll
        for (int i = 0; i < 4; ++i)
            #pragma unroll
            for (int j = 0; j < 2; ++j)
                acc[i][j] = __builtin_amdgcn_mfma_f32_16x16x32_bf16(af[i], bfr[j], acc[i][j], 0, 0, 0);
    }

    #pragma unroll
    for (int i = 0; i < 4; ++i) {
        #pragma unroll
        for (int j = 0; j < 2; ++j) {
            const int col = ncol + j * 16 + lr;
            const float bb = bias[col];
            #pragma unroll
            for (int r = 0; r < 4; ++r) {
                const int row = mrow + i * 16 + lg * 4 + r;  // m89-verified C/D layout
                out[(size_t)row * DOUT + col] = acc[i][j][r] + bb;
            }
        }
    }
}

extern "C" void kernel_launch(void* const* d_in, const int* in_sizes, int n_in,
                              void* d_out, int out_size, void* d_ws, size_t ws_size,
                              hipStream_t stream) {
    const float* Q  = (const float*)d_in[0];
    const float* K  = (const float*)d_in[1];
    const int*   td = (const int*)d_in[2];
    const float* Wo = (const float*)d_in[3];
    const float* bo = (const float*)d_in[4];
    float* out = (float*)d_out;

    unsigned short* ctxb = (unsigned short*)d_ws;                  // 16384*512*2 = 16.8 MB
    unsigned short* Wt   = ctxb + (size_t)B_SEG * DKDIM;           // + 0.5 MB

    hipLaunchKernelGGL(wt_kernel,  dim3(DOUT), dim3(256), 0, stream, Wo, Wt);
    // ATTRIBUTION (this round only): attn launched twice — idempotent, second
    // pass rewrites identical ctxb. dur_us delta vs round 2 ≈ attn duration.
    hipLaunchKernelGGL(attn_kernel, dim3(B_SEG / 4), dim3(256), 0, stream, Q, K, td, ctxb);
    hipLaunchKernelGGL(attn_kernel, dim3(B_SEG / 4), dim3(256), 0, stream, Q, K, td, ctxb);
    hipLaunchKernelGGL(proj_kernel, dim3((B_SEG / 64) * (DOUT / 32) / 4), dim3(256), 0, stream,
                       ctxb, Wt, bo, out);
}

// Round 4
// 194.581 us; speedup vs baseline: 1.7510x; 1.7510x over previous
//
#include <hip/hip_runtime.h>
#include <hip/hip_bf16.h>

#define B_SEG 16384
#define R_EDGE 262144
#define DKDIM 512
#define DOUT 512

typedef __attribute__((ext_vector_type(4))) float f32x4;
typedef __attribute__((ext_vector_type(8))) short bf16x8;

static __device__ __forceinline__ unsigned short f2bf(float f) {
    union { float f; unsigned int u; } v; v.f = f;
    unsigned int r = (v.u + 0x7FFFu + ((v.u >> 16) & 1u)) >> 16;
    return (unsigned short)r;
}

static __device__ __forceinline__ float dot8(const float4 qa, const float4 qb,
                                             const float4 ka, const float4 kb) {
    return qa.x * ka.x + qa.y * ka.y + qa.z * ka.z + qa.w * ka.w
         + qb.x * kb.x + qb.y * kb.y + qb.z * kb.z + qb.w * kb.w;
}

// ---------------- Stage 1: fused segment attention ---------------------------
// ONE SEGMENT = ONE 64-THREAD BLOCK: finished segments release their SIMD slot
// immediately (wave-level load balance; segment lengths are Binomial, mean 16,
// sigma 4 — 4-wave blocks would idle on the max of 4).
// Online softmax over the segment's K rows; K read exactly once from HBM.
__global__ __launch_bounds__(64, 4) void attn_kernel(
    const float* __restrict__ Q, const float* __restrict__ K,
    const int* __restrict__ td, unsigned short* __restrict__ ctxb)
{
    const int lane = threadIdx.x & 63;
    const int b = blockIdx.x;

    // lower_bound(td, b) and lower_bound(td, b+1) — td is sorted.
    int lo = 0, hi = R_EDGE;
    while (lo < hi) { int mid = (lo + hi) >> 1; if (td[mid] < b) lo = mid + 1; else hi = mid; }
    const int s0 = lo;
    hi = R_EDGE;
    while (lo < hi) { int mid = (lo + hi) >> 1; if (td[mid] < b + 1) lo = mid + 1; else hi = mid; }
    const int s1 = lo;

    // Q row: lane holds elems [4*lane .. 4*lane+3] and [256+4*lane .. +3]
    const float4* Q4 = (const float4*)(Q + (size_t)b * DKDIM);
    const float4 qa = Q4[lane];
    const float4 qb = Q4[64 + lane];

    float m = -INFINITY, l = 0.0f;
    float c0 = 0.f, c1 = 0.f, c2 = 0.f, c3 = 0.f;
    float c4 = 0.f, c5 = 0.f, c6 = 0.f, c7 = 0.f;

    float4 ka0, kb0, ka1, kb1, ka2, kb2, ka3, kb3;

#define LOAD4(dst_a0, dst_b0, dst_a1, dst_b1, dst_a2, dst_b2, dst_a3, dst_b3, ee)            \
    {                                                                                        \
        const float4* K0_ = (const float4*)(K + (size_t)((ee) + 0) * DKDIM);                 \
        const float4* K1_ = (const float4*)(K + (size_t)((ee) + 1) * DKDIM);                 \
        const float4* K2_ = (const float4*)(K + (size_t)((ee) + 2) * DKDIM);                 \
        const float4* K3_ = (const float4*)(K + (size_t)((ee) + 3) * DKDIM);                 \
        dst_a0 = K0_[lane]; dst_b0 = K0_[64 + lane];                                         \
        dst_a1 = K1_[lane]; dst_b1 = K1_[64 + lane];                                         \
        dst_a2 = K2_[lane]; dst_b2 = K2_[64 + lane];                                         \
        dst_a3 = K3_[lane]; dst_b3 = K3_[64 + lane];                                         \
    }

#define PROC4()                                                                              \
    {                                                                                        \
        float p0 = dot8(qa, qb, ka0, kb0);                                                   \
        float p1 = dot8(qa, qb, ka1, kb1);                                                   \
        float p2 = dot8(qa, qb, ka2, kb2);                                                   \
        float p3 = dot8(qa, qb, ka3, kb3);                                                   \
        _Pragma("unroll")                                                                    \
        for (int off = 32; off >= 1; off >>= 1) {                                            \
            p0 += __shfl_xor(p0, off, 64);                                                   \
            p1 += __shfl_xor(p1, off, 64);                                                   \
            p2 += __shfl_xor(p2, off, 64);                                                   \
            p3 += __shfl_xor(p3, off, 64);                                                   \
        }                                                                                    \
        const float nm = fmaxf(fmaxf(fmaxf(p0, p1), fmaxf(p2, p3)), m);                      \
        const float sc = __expf(m - nm);                                                     \
        const float w0 = __expf(p0 - nm), w1 = __expf(p1 - nm);                              \
        const float w2 = __expf(p2 - nm), w3 = __expf(p3 - nm);                              \
        l = l * sc + ((w0 + w1) + (w2 + w3));                                                \
        c0 = c0 * sc + (w0 * ka0.x + w1 * ka1.x) + (w2 * ka2.x + w3 * ka3.x);                \
        c1 = c1 * sc + (w0 * ka0.y + w1 * ka1.y) + (w2 * ka2.y + w3 * ka3.y);                \
        c2 = c2 * sc + (w0 * ka0.z + w1 * ka1.z) + (w2 * ka2.z + w3 * ka3.z);                \
        c3 = c3 * sc + (w0 * ka0.w + w1 * ka1.w) + (w2 * ka2.w + w3 * ka3.w);                \
        c4 = c4 * sc + (w0 * kb0.x + w1 * kb1.x) + (w2 * kb2.x + w3 * kb3.x);                \
        c5 = c5 * sc + (w0 * kb0.y + w1 * kb1.y) + (w2 * kb2.y + w3 * kb3.y);                \
        c6 = c6 * sc + (w0 * kb0.z + w1 * kb1.z) + (w2 * kb2.z + w3 * kb3.z);                \
        c7 = c7 * sc + (w0 * kb0.w + w1 * kb1.w) + (w2 * kb2.w + w3 * kb3.w);                \
        m = nm;                                                                              \
    }

    int e = s0;
    if (s1 - s0 >= 4) {
        LOAD4(ka0, kb0, ka1, kb1, ka2, kb2, ka3, kb3, e);
        for (; e + 7 < s1; e += 4) {
            float4 na0, nb0, na1, nb1, na2, nb2, na3, nb3;
            LOAD4(na0, nb0, na1, nb1, na2, nb2, na3, nb3, e + 4);   // prefetch next
            PROC4();                                                 // compute current
            ka0 = na0; kb0 = nb0; ka1 = na1; kb1 = nb1;
            ka2 = na2; kb2 = nb2; ka3 = na3; kb3 = nb3;
        }
        PROC4();
        e += 4;
    }
    for (; e < s1; ++e) {
        const float4* K4 = (const float4*)(K + (size_t)e * DKDIM);
        const float4 ka = K4[lane];
        const float4 kb = K4[64 + lane];
        float p = dot8(qa, qb, ka, kb);
        #pragma unroll
        for (int off = 32; off >= 1; off >>= 1) p += __shfl_xor(p, off, 64);
        const float nm  = fmaxf(m, p);
        const float sc  = __expf(m - nm);
        const float wgt = __expf(p - nm);
        l = l * sc + wgt;
        c0 = c0 * sc + wgt * ka.x;  c1 = c1 * sc + wgt * ka.y;
        c2 = c2 * sc + wgt * ka.z;  c3 = c3 * sc + wgt * ka.w;
        c4 = c4 * sc + wgt * kb.x;  c5 = c5 * sc + wgt * kb.y;
        c6 = c6 * sc + wgt * kb.z;  c7 = c7 * sc + wgt * kb.w;
        m = nm;
    }

    const float rin = (s1 > s0) ? (1.0f / l) : 0.0f;  // empty segment -> ctx = 0
    ushort4 oa, ob;
    oa.x = f2bf(c0 * rin); oa.y = f2bf(c1 * rin); oa.z = f2bf(c2 * rin); oa.w = f2bf(c3 * rin);
    ob.x = f2bf(c4 * rin); ob.y = f2bf(c5 * rin); ob.z = f2bf(c6 * rin); ob.w = f2bf(c7 * rin);
    ushort4* O4 = (ushort4*)(ctxb + (size_t)b * DKDIM);
    O4[lane]      = oa;
    O4[64 + lane] = ob;
}

// ---------------- Stage 2a: W_o -> bf16, transposed (n-major) ----------------
__global__ __launch_bounds__(256) void wt_kernel(const float* __restrict__ W,
                                                 unsigned short* __restrict__ Wt)
{
    const int n = blockIdx.x;       // 512 blocks: one output column each
    for (int k = threadIdx.x; k < DKDIM; k += 256)
        Wt[(size_t)n * DKDIM + k] = f2bf(W[(size_t)k * DOUT + n]);
}

// ---------------- Stage 2b: out = ctx @ W_o + b_o via bf16 MFMA --------------
// No LDS: fragments read directly from L2-resident ctx-bf16 and Wt.
// Each wave computes a 64x32 output tile (4 m-frags x 2 n-frags).
// XCD-aware block swizzle: 128 consecutive block-ids per XCD -> each XCD's
// working set is 32 m-tiles of A (2 MB) + all of B (0.5 MB), L2-resident.
__global__ __launch_bounds__(256) void proj_kernel(
    const unsigned short* __restrict__ A,   // ctx bf16, [16384][512] row-major
    const unsigned short* __restrict__ Bt,  // W_o^T bf16, [512 n][512 k]
    const float* __restrict__ bias, float* __restrict__ out)
{
    const int w = threadIdx.x >> 6, lane = threadIdx.x & 63;
    // bijective XCD swizzle: gridDim.x = 1024, 1024 % 8 == 0
    const int cpx = (int)gridDim.x >> 3;    // 128 blocks per XCD chunk
    const int bid = (blockIdx.x & 7) * cpx + (blockIdx.x >> 3);
    const int gw   = bid * 4 + w;           // 0..4095
    const int mrow = (gw >> 4) << 6;        // 256 row-tiles of 64
    const int ncol = (gw & 15) << 5;        // 16 col-tiles of 32
    const int lr = lane & 15, lg = lane >> 4;

    f32x4 acc[4][2];
    #pragma unroll
    for (int i = 0; i < 4; ++i)
        #pragma unroll
        for (int j = 0; j < 2; ++j)
            acc[i][j] = (f32x4){0.f, 0.f, 0.f, 0.f};

    for (int k0 = 0; k0 < DKDIM; k0 += 32) {
        const int koff = k0 + lg * 8;
        bf16x8 af[4], bfr[2];
        #pragma unroll
        for (int i = 0; i < 4; ++i)
            af[i] = *(const bf16x8*)(A + (size_t)(mrow + i * 16 + lr) * DKDIM + koff);
        #pragma unroll
        for (int j = 0; j < 2; ++j)
            bfr[j] = *(const bf16x8*)(Bt + (size_t)(ncol + j * 16 + lr) * DKDIM + koff);
        #pragma unroll
        for (int i = 0; i < 4; ++i)
            #pragma unroll
            for (int j = 0; j < 2; ++j)
                acc[i][j] = __builtin_amdgcn_mfma_f32_16x16x32_bf16(af[i], bfr[j], acc[i][j], 0, 0, 0);
    }

    #pragma unroll
    for (int i = 0; i < 4; ++i) {
        #pragma unroll
        for (int j = 0; j < 2; ++j) {
            const int col = ncol + j * 16 + lr;
            const float bb = bias[col];
            #pragma unroll
            for (int r = 0; r < 4; ++r) {
                const int row = mrow + i * 16 + lg * 4 + r;  // m89-verified C/D layout
                out[(size_t)row * DOUT + col] = acc[i][j][r] + bb;
            }
        }
    }
}

extern "C" void kernel_launch(void* const* d_in, const int* in_sizes, int n_in,
                              void* d_out, int out_size, void* d_ws, size_t ws_size,
                              hipStream_t stream) {
    const float* Q  = (const float*)d_in[0];
    const float* K  = (const float*)d_in[1];
    const int*   td = (const int*)d_in[2];
    const float* Wo = (const float*)d_in[3];
    const float* bo = (const float*)d_in[4];
    float* out = (float*)d_out;

    unsigned short* ctxb = (unsigned short*)d_ws;                  // 16384*512*2 = 16.8 MB
    unsigned short* Wt   = ctxb + (size_t)B_SEG * DKDIM;           // + 0.5 MB

    hipLaunchKernelGGL(wt_kernel,  dim3(DOUT), dim3(256), 0, stream, Wo, Wt);
    hipLaunchKernelGGL(attn_kernel, dim3(B_SEG), dim3(64), 0, stream, Q, K, td, ctxb);
    hipLaunchKernelGGL(proj_kernel, dim3((B_SEG / 64) * (DOUT / 32) / 4), dim3(256), 0, stream,
                       ctxb, Wt, bo, out);
}

// Round 5
// 178.177 us; speedup vs baseline: 1.9122x; 1.0921x over previous
//
#include <hip/hip_runtime.h>
#include <hip/hip_bf16.h>

#define B_SEG 16384
#define R_EDGE 262144
#define DKDIM 512
#define DOUT 512

typedef __attribute__((ext_vector_type(4))) float f32x4;
typedef __attribute__((ext_vector_type(8))) short bf16x8;

static __device__ __forceinline__ unsigned short f2bf(float f) {
    union { float f; unsigned int u; } v; v.f = f;
    unsigned int r = (v.u + 0x7FFFu + ((v.u >> 16) & 1u)) >> 16;
    return (unsigned short)r;
}

static __device__ __forceinline__ float dot8(const float4 qa, const float4 qb,
                                             const float4 ka, const float4 kb) {
    return qa.x * ka.x + qa.y * ka.y + qa.z * ka.z + qa.w * ka.w
         + qb.x * kb.x + qb.y * kb.y + qb.z * kb.z + qb.w * kb.w;
}

// ---------------- Stage 0: segment-start table (parallel scatter) ------------
// starts[b] = lower_bound(td, b); starts[B_SEG] = R_EDGE. td sorted -> the
// ranges (td[e-1], td[e]] are disjoint across threads, no races.
__global__ __launch_bounds__(256) void starts_kernel(const int* __restrict__ td,
                                                     int* __restrict__ starts)
{
    const int e = blockIdx.x * 256 + threadIdx.x;
    if (e >= R_EDGE) return;
    const int cur  = td[e];
    const int prev = (e == 0) ? -1 : td[e - 1];
    for (int b = prev + 1; b <= cur; ++b) starts[b] = e;
    if (e == R_EDGE - 1)
        for (int b = cur + 1; b <= B_SEG; ++b) starts[b] = R_EDGE;
}

// ---------------- Stage 1: fused segment attention ---------------------------
// ONE SEGMENT = ONE 64-THREAD BLOCK (wave-level load balance). Online softmax;
// K read exactly once from HBM. Segment bounds from the starts table (2
// independent loads instead of 36 serially-dependent binary-search loads).
__global__ __launch_bounds__(64, 4) void attn_kernel(
    const float* __restrict__ Q, const float* __restrict__ K,
    const int* __restrict__ starts, unsigned short* __restrict__ ctxb)
{
    const int lane = threadIdx.x & 63;
    const int b = blockIdx.x;

    const int s0 = starts[b];
    const int s1 = starts[b + 1];

    // Q row: lane holds elems [4*lane .. 4*lane+3] and [256+4*lane .. +3]
    const float4* Q4 = (const float4*)(Q + (size_t)b * DKDIM);
    const float4 qa = Q4[lane];
    const float4 qb = Q4[64 + lane];

    float m = -INFINITY, l = 0.0f;
    float c0 = 0.f, c1 = 0.f, c2 = 0.f, c3 = 0.f;
    float c4 = 0.f, c5 = 0.f, c6 = 0.f, c7 = 0.f;

    float4 ka0, kb0, ka1, kb1, ka2, kb2, ka3, kb3;

#define LOAD4(dst_a0, dst_b0, dst_a1, dst_b1, dst_a2, dst_b2, dst_a3, dst_b3, ee)            \
    {                                                                                        \
        const float4* K0_ = (const float4*)(K + (size_t)((ee) + 0) * DKDIM);                 \
        const float4* K1_ = (const float4*)(K + (size_t)((ee) + 1) * DKDIM);                 \
        const float4* K2_ = (const float4*)(K + (size_t)((ee) + 2) * DKDIM);                 \
        const float4* K3_ = (const float4*)(K + (size_t)((ee) + 3) * DKDIM);                 \
        dst_a0 = K0_[lane]; dst_b0 = K0_[64 + lane];                                         \
        dst_a1 = K1_[lane]; dst_b1 = K1_[64 + lane];                                         \
        dst_a2 = K2_[lane]; dst_b2 = K2_[64 + lane];                                         \
        dst_a3 = K3_[lane]; dst_b3 = K3_[64 + lane];                                         \
    }

#define PROC4()                                                                              \
    {                                                                                        \
        float p0 = dot8(qa, qb, ka0, kb0);                                                   \
        float p1 = dot8(qa, qb, ka1, kb1);                                                   \
        float p2 = dot8(qa, qb, ka2, kb2);                                                   \
        float p3 = dot8(qa, qb, ka3, kb3);                                                   \
        _Pragma("unroll")                                                                    \
        for (int off = 32; off >= 1; off >>= 1) {                                            \
            p0 += __shfl_xor(p0, off, 64);                                                   \
            p1 += __shfl_xor(p1, off, 64);                                                   \
            p2 += __shfl_xor(p2, off, 64);                                                   \
            p3 += __shfl_xor(p3, off, 64);                                                   \
        }                                                                                    \
        const float nm = fmaxf(fmaxf(fmaxf(p0, p1), fmaxf(p2, p3)), m);                      \
        const float sc = __expf(m - nm);                                                     \
        const float w0 = __expf(p0 - nm), w1 = __expf(p1 - nm);                              \
        const float w2 = __expf(p2 - nm), w3 = __expf(p3 - nm);                              \
        l = l * sc + ((w0 + w1) + (w2 + w3));                                                \
        c0 = c0 * sc + (w0 * ka0.x + w1 * ka1.x) + (w2 * ka2.x + w3 * ka3.x);                \
        c1 = c1 * sc + (w0 * ka0.y + w1 * ka1.y) + (w2 * ka2.y + w3 * ka3.y);                \
        c2 = c2 * sc + (w0 * ka0.z + w1 * ka1.z) + (w2 * ka2.z + w3 * ka3.z);                \
        c3 = c3 * sc + (w0 * ka0.w + w1 * ka1.w) + (w2 * ka2.w + w3 * ka3.w);                \
        c4 = c4 * sc + (w0 * kb0.x + w1 * kb1.x) + (w2 * kb2.x + w3 * kb3.x);                \
        c5 = c5 * sc + (w0 * kb0.y + w1 * kb1.y) + (w2 * kb2.y + w3 * kb3.y);                \
        c6 = c6 * sc + (w0 * kb0.z + w1 * kb1.z) + (w2 * kb2.z + w3 * kb3.z);                \
        c7 = c7 * sc + (w0 * kb0.w + w1 * kb1.w) + (w2 * kb2.w + w3 * kb3.w);                \
        m = nm;                                                                              \
    }

    int e = s0;
    if (s1 - s0 >= 4) {
        LOAD4(ka0, kb0, ka1, kb1, ka2, kb2, ka3, kb3, e);
        for (; e + 7 < s1; e += 4) {
            float4 na0, nb0, na1, nb1, na2, nb2, na3, nb3;
            LOAD4(na0, nb0, na1, nb1, na2, nb2, na3, nb3, e + 4);   // prefetch next
            PROC4();                                                 // compute current
            ka0 = na0; kb0 = nb0; ka1 = na1; kb1 = nb1;
            ka2 = na2; kb2 = nb2; ka3 = na3; kb3 = nb3;
        }
        PROC4();
        e += 4;
    }
    for (; e < s1; ++e) {
        const float4* K4 = (const float4*)(K + (size_t)e * DKDIM);
        const float4 ka = K4[lane];
        const float4 kb = K4[64 + lane];
        float p = dot8(qa, qb, ka, kb);
        #pragma unroll
        for (int off = 32; off >= 1; off >>= 1) p += __shfl_xor(p, off, 64);
        const float nm  = fmaxf(m, p);
        const float sc  = __expf(m - nm);
        const float wgt = __expf(p - nm);
        l = l * sc + wgt;
        c0 = c0 * sc + wgt * ka.x;  c1 = c1 * sc + wgt * ka.y;
        c2 = c2 * sc + wgt * ka.z;  c3 = c3 * sc + wgt * ka.w;
        c4 = c4 * sc + wgt * kb.x;  c5 = c5 * sc + wgt * kb.y;
        c6 = c6 * sc + wgt * kb.z;  c7 = c7 * sc + wgt * kb.w;
        m = nm;
    }

    const float rin = (s1 > s0) ? (1.0f / l) : 0.0f;  // empty segment -> ctx = 0
    ushort4 oa, ob;
    oa.x = f2bf(c0 * rin); oa.y = f2bf(c1 * rin); oa.z = f2bf(c2 * rin); oa.w = f2bf(c3 * rin);
    ob.x = f2bf(c4 * rin); ob.y = f2bf(c5 * rin); ob.z = f2bf(c6 * rin); ob.w = f2bf(c7 * rin);
    ushort4* O4 = (ushort4*)(ctxb + (size_t)b * DKDIM);
    O4[lane]      = oa;
    O4[64 + lane] = ob;
}

// ---------------- Stage 2a: W_o -> bf16 transposed, LDS tile transpose -------
// 64x64 tiles; coalesced global read AND write; LDS stride 68 ushorts ->
// 2-way bank aliasing only (free on CDNA4, m136).
__global__ __launch_bounds__(256) void wt_kernel(const float* __restrict__ W,
                                                 unsigned short* __restrict__ Wt)
{
    __shared__ unsigned short tile[64][68];
    const int n0 = (blockIdx.x & 7) * 64;
    const int k0 = (blockIdx.x >> 3) * 64;
    const int tx = threadIdx.x & 63, g = threadIdx.x >> 6;  // g in 0..3

    #pragma unroll
    for (int dy = 0; dy < 16; ++dy) {
        const int k = g * 16 + dy;
        tile[tx][k] = f2bf(W[(size_t)(k0 + k) * DOUT + n0 + tx]);  // coalesced over tx
    }
    __syncthreads();
    #pragma unroll
    for (int dr = 0; dr < 16; ++dr) {
        const int r = g * 16 + dr;
        Wt[(size_t)(n0 + r) * DKDIM + k0 + tx] = tile[r][tx];      // coalesced over tx
    }
}

// ---------------- Stage 2b: out = ctx @ W_o + b_o via bf16 MFMA --------------
// No LDS: fragments read directly from L2/L3-resident ctx-bf16 and Wt.
// Each wave: 64x32 output tile (4 m-frags x 2 n-frags). Explicit 2-stage
// register double-buffer (named bufs, static indexing) hides L2/L3 latency
// under the previous step's MFMAs. XCD-aware bijective block swizzle.
__global__ __launch_bounds__(256, 4) void proj_kernel(
    const unsigned short* __restrict__ A,   // ctx bf16, [16384][512] row-major
    const unsigned short* __restrict__ Bt,  // W_o^T bf16, [512 n][512 k]
    const float* __restrict__ bias, float* __restrict__ out)
{
    const int w = threadIdx.x >> 6, lane = threadIdx.x & 63;
    const int cpx = (int)gridDim.x >> 3;    // 1024 % 8 == 0 -> bijective
    const int bid = (blockIdx.x & 7) * cpx + (blockIdx.x >> 3);
    const int gw   = bid * 4 + w;           // 0..4095
    const int mrow = (gw >> 4) << 6;        // 256 row-tiles of 64
    const int ncol = (gw & 15) << 5;        // 16 col-tiles of 32
    const int lr = lane & 15, lg = lane >> 4;

    f32x4 acc[4][2];
    #pragma unroll
    for (int i = 0; i < 4; ++i)
        #pragma unroll
        for (int j = 0; j < 2; ++j)
            acc[i][j] = (f32x4){0.f, 0.f, 0.f, 0.f};

#define LOADK(aa, bb, kk)                                                                     \
    {                                                                                         \
        const int koff = (kk) + lg * 8;                                                       \
        _Pragma("unroll")                                                                     \
        for (int i = 0; i < 4; ++i)                                                           \
            aa[i] = *(const bf16x8*)(A + (size_t)(mrow + i * 16 + lr) * DKDIM + koff);        \
        _Pragma("unroll")                                                                     \
        for (int j = 0; j < 2; ++j)                                                           \
            bb[j] = *(const bf16x8*)(Bt + (size_t)(ncol + j * 16 + lr) * DKDIM + koff);       \
    }

#define MFMAK(aa, bb)                                                                         \
    {                                                                                         \
        _Pragma("unroll")                                                                     \
        for (int i = 0; i < 4; ++i)                                                           \
            _Pragma("unroll")                                                                 \
            for (int j = 0; j < 2; ++j)                                                       \
                acc[i][j] = __builtin_amdgcn_mfma_f32_16x16x32_bf16(aa[i], bb[j],             \
                                                                    acc[i][j], 0, 0, 0);      \
    }

    bf16x8 a0[4], b0[2], a1[4], b1[2];
    LOADK(a0, b0, 0);
    #pragma unroll
    for (int k0 = 0; k0 < DKDIM; k0 += 64) {
        LOADK(a1, b1, k0 + 32);                       // prefetch odd step
        MFMAK(a0, b0);
        if (k0 + 64 < DKDIM) LOADK(a0, b0, k0 + 64);  // prefetch next even step
        MFMAK(a1, b1);
    }

    #pragma unroll
    for (int i = 0; i < 4; ++i) {
        #pragma unroll
        for (int j = 0; j < 2; ++j) {
            const int col = ncol + j * 16 + lr;
            const float bb = bias[col];
            #pragma unroll
            for (int r = 0; r < 4; ++r) {
                const int row = mrow + i * 16 + lg * 4 + r;  // m89-verified C/D layout
                out[(size_t)row * DOUT + col] = acc[i][j][r] + bb;
            }
        }
    }
}

extern "C" void kernel_launch(void* const* d_in, const int* in_sizes, int n_in,
                              void* d_out, int out_size, void* d_ws, size_t ws_size,
                              hipStream_t stream) {
    const float* Q  = (const float*)d_in[0];
    const float* K  = (const float*)d_in[1];
    const int*   td = (const int*)d_in[2];
    const float* Wo = (const float*)d_in[3];
    const float* bo = (const float*)d_in[4];
    float* out = (float*)d_out;

    unsigned short* ctxb = (unsigned short*)d_ws;                  // 16.8 MB
    unsigned short* Wt   = ctxb + (size_t)B_SEG * DKDIM;           // + 0.5 MB
    int* starts = (int*)(Wt + (size_t)DOUT * DKDIM);               // + 64 KB

    hipLaunchKernelGGL(starts_kernel, dim3(R_EDGE / 256), dim3(256), 0, stream, td, starts);
    hipLaunchKernelGGL(wt_kernel,     dim3(64), dim3(256), 0, stream, Wo, Wt);
    hipLaunchKernelGGL(attn_kernel,   dim3(B_SEG), dim3(64), 0, stream, Q, K, starts, ctxb);
    hipLaunchKernelGGL(proj_kernel,   dim3((B_SEG / 64) * (DOUT / 32) / 4), dim3(256), 0, stream,
                       ctxb, Wt, bo, out);
}